// Round 21
// baseline (316.729 us; speedup 1.0000x reference)
//
#include <hip/hip_runtime.h>
#include <hip/hip_bf16.h>
#include <math.h>

#define NB 8192
#define S_ 45
#define D_ 64
#define FF_ 256
#define LDH 68     // f32 row stride t1/t2
#define HBS 72     // bf16 row stride hb/qb/kb/ob (144 B)
#define VTS 72     // bf16 row stride vT [72][72]
#define FBS 280    // bf16 row stride fb full tile [48][280]
#define EPB 38016  // per-element LDS pool bytes

typedef __attribute__((ext_vector_type(4))) float f32x4;
typedef __attribute__((ext_vector_type(8))) short s16x8;
typedef __attribute__((ext_vector_type(4))) short s16x4;

// ws layout (bytes): pe f32 [45*64] @0 ; WqkvT bf16 [192][64] @11520 ;
// WoT bf16 [64][64] @36096 ; W1T bf16 [256][64] @44288 ; W2T bf16 [64][256] @77056
#define WS_QKV 11520
#define WS_WO  36096
#define WS_W1  44288
#define WS_W2  77056

__device__ inline short f2bf(float f) {   // HW RNE f32->bf16
    __hip_bfloat16 h = __float2bfloat16(f);
    return *reinterpret_cast<short*>(&h);
}
__device__ inline float bf2f(short s) {
    union { unsigned u; float f; } c;
    c.u = ((unsigned)(unsigned short)s) << 16;
    return c.f;
}

__global__ void prep_kernel(const float* __restrict__ Wq, const float* __restrict__ Wk,
                            const float* __restrict__ Wv, const float* __restrict__ Wo,
                            const float* __restrict__ W1, const float* __restrict__ W2,
                            void* __restrict__ ws) {
    float* pe   = (float*)ws;
    short* wqkv = (short*)((char*)ws + WS_QKV);
    short* wo   = (short*)((char*)ws + WS_WO);
    short* w1   = (short*)((char*)ws + WS_W1);
    short* w2   = (short*)((char*)ws + WS_W2);
    int i = blockIdx.x * 256 + threadIdx.x;
    if (i < S_ * D_) {                       // positional encoding (f32)
        int s = i / D_, d = i % D_;
        float div = expf(-logf(10000.0f) * (float)(d & ~1) / (float)D_);
        float ang = (float)s * div;
        pe[i] = (d & 1) ? cosf(ang) : sinf(ang);
    }
    if (i < 12288) {                         // WqkvT[n][k] = W{q,k,v}[k][n&63]
        int n = i >> 6, k = i & 63;
        const float* W = (n < 64) ? Wq : (n < 128 ? Wk : Wv);
        wqkv[i] = f2bf(W[k * 64 + (n & 63)]);
    }
    if (i < 4096) {                          // WoT[n][k] = Wo[k][n]
        int n = i >> 6, k = i & 63;
        wo[i] = f2bf(Wo[k * 64 + n]);
    }
    if (i < 16384) {
        int n = i >> 6, k = i & 63;          // W1T[n][k] = W1[k][n]
        w1[i] = f2bf(W1[k * FF_ + n]);
        int n2 = i >> 8, k2 = i & 255;       // W2T[n][k] = W2[k][n]
        w2[i] = f2bf(W2[k2 * 64 + n2]);
    }
}

__launch_bounds__(512, 1)
__global__ void encoder_kernel(
    const float* __restrict__ x,
    const float* __restrict__ bq, const float* __restrict__ bk,
    const float* __restrict__ bv, const float* __restrict__ bo,
    const float* __restrict__ ln1g, const float* __restrict__ ln1b,
    const float* __restrict__ b1, const float* __restrict__ b2,
    const float* __restrict__ ln2g, const float* __restrict__ ln2b,
    const void* __restrict__ ws,
    float* __restrict__ out)
{
    const float* pe    = (const float*)ws;
    const short* wqkvT = (const short*)((const char*)ws + WS_QKV);
    const short* woT   = (const short*)((const char*)ws + WS_WO);
    const short* w1T   = (const short*)((const char*)ws + WS_W1);
    const short* w2T   = (const short*)((const char*)ws + WS_W2);

    // TWO elements per block: waves 0-3 -> element A, waves 4-7 -> element B.
    // Each element owns a 38016 B pool half (layout identical to R16/R19):
    //  @0 hb ; @6912 qb|t1/t2|fb ; @13824 kb ; @20736 vT ; @31104 ob
    // 76 KB -> 2 blocks/CU; barriers per ELEMENT halve (8 barriers serve 2).
    __shared__ __align__(16) char pool[2 * EPB];

    const int t = threadIdx.x;
    const int w = t >> 6, l = t & 63;
    const int lr = l & 15, lg = l >> 4;   // MFMA frag coords
    const int elem = w >> 2;              // 0 or 1
    const int we   = w & 3;               // wave within element
    const int te   = t & 255;             // thread within element
    const size_t e = (size_t)blockIdx.x * 2 + elem;   // batch element index

    char* ep = pool + elem * EPB;
    short* hb = (short*)ep;
    short* qb = (short*)(ep + 6912);
    short* kb = (short*)(ep + 13824);
    short* vT = (short*)(ep + 20736);
    short* ob = (short*)(ep + 31104);
    float* t1 = (float*)(ep + 6912);
    short* fb = (short*)(ep + 6912);
    float* t2 = (float*)(ep + 6912);

    const s16x8 zero8 = {0, 0, 0, 0, 0, 0, 0, 0};

    // ---- 1. h = x + pe -> hb (bf16); zero pad rows ---------------------
    {
        const float4* x4 = (const float4*)(x + e * (S_ * D_));
        const float4* p4 = (const float4*)pe;
        for (int i = te; i < S_ * D_ / 4; i += 256) {
            int r = i >> 4, c4 = (i & 15) << 2;
            float4 a = x4[i], p = p4[i];
            s16x4 hv16 = { f2bf(a.x + p.x), f2bf(a.y + p.y),
                           f2bf(a.z + p.z), f2bf(a.w + p.w) };
            *(s16x4*)&hb[r * HBS + c4] = hv16;
        }
        for (int i = te; i < 3 * HBS; i += 256) hb[45 * HBS + i] = 0;
    }
    __syncthreads();                                     // B1

    // ---- 2. fused QKV via MFMA (9 tiles/wave) --------------------------
    {
        const float SC2 = 0.35355339059327373f * 1.44269504088896340f; // 1/sqrt(8)*log2e
        for (int id = we; id < 36; id += 4) {
            const int m0 = (id % 3) << 4, n0 = (id / 3) << 4;
            f32x4 acc = {0.f, 0.f, 0.f, 0.f};
            #pragma unroll
            for (int k0 = 0; k0 < 64; k0 += 32) {
                s16x8 af = *(const s16x8*)&hb[(m0 + lr) * HBS + k0 + lg * 8];
                s16x8 bf = *(const s16x8*)&wqkvT[(n0 + lr) * 64 + k0 + lg * 8];
                acc = __builtin_amdgcn_mfma_f32_16x16x32_bf16(af, bf, acc, 0, 0, 0);
            }
            if (n0 < 64) {                       // q' = (q+bq)*SC2
                const float bias = bq[n0 + lr];
                #pragma unroll
                for (int r = 0; r < 4; ++r)
                    qb[(m0 + lg * 4 + r) * HBS + n0 + lr] = f2bf((acc[r] + bias) * SC2);
            } else if (n0 < 128) {               // k
                const int cc = n0 - 64 + lr;
                const float bias = bk[cc];
                #pragma unroll
                for (int r = 0; r < 4; ++r)
                    kb[(m0 + lg * 4 + r) * HBS + cc] = f2bf(acc[r] + bias);
            } else {                             // v -> vT[d][kr] (K-axis pads
                const int cc = n0 - 128 + lr;    //  finite; P masks kr>=45)
                const float bias = bv[cc];
                s16x4 vv = { f2bf(acc[0] + bias), f2bf(acc[1] + bias),
                             f2bf(acc[2] + bias), f2bf(acc[3] + bias) };
                *(s16x4*)&vT[cc * VTS + m0 + lg * 4] = vv;
            }
        }
    }
    __syncthreads();                                     // B2

    // ---- 3. attention: swapped QK^T + in-reg softmax; 2 heads/wave -----
    {
        for (int hh = 0; hh < 2; ++hh) {
            const int hd = (we + (hh << 2)) << 3;        // heads we, we+4
            s16x8 pv_b0 = *(const s16x8*)&vT[(hd + lr) * VTS + lg * 8];      // kr 0-31
            s16x8 pv_b1 = (lg < 2) ? *(const s16x8*)&vT[(hd + lr) * VTS + 32 + lg * 8]
                                   : zero8;                                  // kr 32-47
            s16x8 kaf[3];
            #pragma unroll
            for (int tm = 0; tm < 3; ++tm)
                kaf[tm] = (lg == 0) ? *(const s16x8*)&kb[(tm * 16 + lr) * HBS + hd] : zero8;
            #pragma unroll
            for (int tn = 0; tn < 3; ++tn) {
                s16x8 qbf = (lg == 0) ? *(const s16x8*)&qb[(tn * 16 + lr) * HBS + hd] : zero8;
                f32x4 S[3];
                #pragma unroll
                for (int tm = 0; tm < 3; ++tm) {
                    f32x4 z = {0.f, 0.f, 0.f, 0.f};
                    S[tm] = __builtin_amdgcn_mfma_f32_16x16x32_bf16(kaf[tm], qbf, z, 0, 0, 0);
                }
                float psum = 0.f;
                #pragma unroll
                for (int tm = 0; tm < 3; ++tm) {
                    #pragma unroll
                    for (int r = 0; r < 4; ++r) {
                        float e2 = __builtin_amdgcn_exp2f(S[tm][r]);
                        if (tm == 2) e2 = (lg * 4 + r >= 13) ? 0.f : e2;  // kr>=45
                        S[tm][r] = e2;
                        psum += e2;
                    }
                }
                float s = psum;
                s += __shfl_xor(s, 16);
                s += __shfl_xor(s, 32);
                float inv = 1.0f / s;
                unsigned pk0[3], pk1[3];   // bf16x2 packed P (truncation), per tm
                #pragma unroll
                for (int tm = 0; tm < 3; ++tm) {
                    float a0 = S[tm][0] * inv, a1 = S[tm][1] * inv;
                    float a2 = S[tm][2] * inv, a3 = S[tm][3] * inv;
                    pk0[tm] = (__float_as_uint(a0) >> 16) | (__float_as_uint(a1) & 0xFFFF0000u);
                    pk1[tm] = (__float_as_uint(a2) >> 16) | (__float_as_uint(a3) & 0xFFFF0000u);
                }
                const int srcA = lr + ((lg & 1) << 5);
                const int srcB = srcA + 16;
                unsigned gA0[3], gA1[3], gB0[3], gB1[3];
                #pragma unroll
                for (int tm = 0; tm < 3; ++tm) {
                    gA0[tm] = (unsigned)__shfl((int)pk0[tm], srcA);
                    gA1[tm] = (unsigned)__shfl((int)pk1[tm], srcA);
                    gB0[tm] = (unsigned)__shfl((int)pk0[tm], srcB);
                    gB1[tm] = (unsigned)__shfl((int)pk1[tm], srcB);
                }
                const bool tm1 = (lg >> 1) != 0;
                union { unsigned u[4]; s16x8 v; } a1c, a2c;
                a1c.u[0] = tm1 ? gA0[1] : gA0[0];
                a1c.u[1] = tm1 ? gA1[1] : gA1[0];
                a1c.u[2] = tm1 ? gB0[1] : gB0[0];
                a1c.u[3] = tm1 ? gB1[1] : gB1[0];
                const bool lo = (lg < 2);
                a2c.u[0] = lo ? gA0[2] : 0u;
                a2c.u[1] = lo ? gA1[2] : 0u;
                a2c.u[2] = lo ? gB0[2] : 0u;
                a2c.u[3] = lo ? gB1[2] : 0u;
                f32x4 z = {0.f, 0.f, 0.f, 0.f};
                f32x4 O = __builtin_amdgcn_mfma_f32_16x16x32_bf16(a1c.v, pv_b0, z, 0, 0, 0);
                O = __builtin_amdgcn_mfma_f32_16x16x32_bf16(a2c.v, pv_b1, O, 0, 0, 0);
                if (lr < 8) {
                    #pragma unroll
                    for (int r = 0; r < 4; ++r) {
                        int row = tn * 16 + lg * 4 + r;
                        if (row < S_) ob[row * HBS + hd + lr] = f2bf(O[r]);
                    }
                }
            }
        }
    }
    __syncthreads();                                     // B3

    // ---- 4. t1 = o @ Wo + bo + h (residual), 3 tiles/wave --------------
    {
        for (int id = we; id < 12; id += 4) {
            const int m0 = (id % 3) << 4, n0 = (id / 3) << 4;
            f32x4 acc = {0.f, 0.f, 0.f, 0.f};
            #pragma unroll
            for (int k0 = 0; k0 < 64; k0 += 32) {
                s16x8 af = *(const s16x8*)&ob[(m0 + lr) * HBS + k0 + lg * 8];
                s16x8 bf = *(const s16x8*)&woT[(n0 + lr) * 64 + k0 + lg * 8];
                acc = __builtin_amdgcn_mfma_f32_16x16x32_bf16(af, bf, acc, 0, 0, 0);
            }
            const int col = n0 + lr;
            const float bias = bo[col];
            #pragma unroll
            for (int r = 0; r < 4; ++r) {
                int row = m0 + lg * 4 + r;
                if (row < S_)
                    t1[row * LDH + col] = acc[r] + bias + bf2f(hb[row * HBS + col]);
            }
        }
    }
    __syncthreads();                                     // B4

    // ---- 5. LN1 (8 lanes/row): 360 slots over 256 threads --------------
    {
        for (int slot = te; slot < S_ * 8; slot += 256) {
            const int row = slot >> 3, d0 = (slot & 7) << 3;
            float4 v1 = *(const float4*)&t1[row * LDH + d0];
            float4 v2 = *(const float4*)&t1[row * LDH + d0 + 4];
            float s  = v1.x + v1.y + v1.z + v1.w + v2.x + v2.y + v2.z + v2.w;
            float s2 = v1.x*v1.x + v1.y*v1.y + v1.z*v1.z + v1.w*v1.w +
                       v2.x*v2.x + v2.y*v2.y + v2.z*v2.z + v2.w*v2.w;
            s  += __shfl_xor(s, 1);  s  += __shfl_xor(s, 2);  s  += __shfl_xor(s, 4);
            s2 += __shfl_xor(s2, 1); s2 += __shfl_xor(s2, 2); s2 += __shfl_xor(s2, 4);
            float mean = s * (1.0f / 64.0f);
            float var  = s2 * (1.0f / 64.0f) - mean * mean;
            float rstd = rsqrtf(var + 1e-5f);
            float4 g1 = *(const float4*)&ln1g[d0], g2 = *(const float4*)&ln1g[d0 + 4];
            float4 b1v = *(const float4*)&ln1b[d0], b2v = *(const float4*)&ln1b[d0 + 4];
            s16x8 o16;
            o16[0] = f2bf((v1.x - mean) * rstd * g1.x + b1v.x);
            o16[1] = f2bf((v1.y - mean) * rstd * g1.y + b1v.y);
            o16[2] = f2bf((v1.z - mean) * rstd * g1.z + b1v.z);
            o16[3] = f2bf((v1.w - mean) * rstd * g1.w + b1v.w);
            o16[4] = f2bf((v2.x - mean) * rstd * g2.x + b2v.x);
            o16[5] = f2bf((v2.y - mean) * rstd * g2.y + b2v.y);
            o16[6] = f2bf((v2.z - mean) * rstd * g2.z + b2v.z);
            o16[7] = f2bf((v2.w - mean) * rstd * g2.w + b2v.w);
            *(s16x8*)&hb[row * HBS + d0] = o16;
        }
    }
    __syncthreads();                                     // B5

    // ---- 6. FFN1 full-width, 12 tiles/wave ------------------------------
    {
        for (int id = we; id < 48; id += 4) {
            const int m0 = (id % 3) << 4, nl = (id / 3) << 4;
            f32x4 acc = {0.f, 0.f, 0.f, 0.f};
            #pragma unroll
            for (int k0 = 0; k0 < 64; k0 += 32) {
                s16x8 af = *(const s16x8*)&hb[(m0 + lr) * HBS + k0 + lg * 8];
                s16x8 bf = *(const s16x8*)&w1T[(nl + lr) * 64 + k0 + lg * 8];
                acc = __builtin_amdgcn_mfma_f32_16x16x32_bf16(af, bf, acc, 0, 0, 0);
            }
            const float bias = b1[nl + lr];
            #pragma unroll
            for (int r = 0; r < 4; ++r) {
                int row = m0 + lg * 4 + r;
                if (row < S_)
                    fb[row * FBS + nl + lr] = f2bf(fmaxf(acc[r] + bias, 0.f));
            }
        }
    }
    __syncthreads();                                     // B6

    // ---- 7. FFN2 full-K, 3 tiles/wave (accs live across B7) ------------
    f32x4 fa0 = {0.f, 0.f, 0.f, 0.f};
    f32x4 fa1 = {0.f, 0.f, 0.f, 0.f};
    f32x4 fa2 = {0.f, 0.f, 0.f, 0.f};
    {
        const int i0 = we, i1 = we + 4, i2 = we + 8;
        {
            const int m0 = (i0 % 3) << 4, n0 = (i0 / 3) << 4;
            #pragma unroll 4
            for (int k0 = 0; k0 < FF_; k0 += 32) {
                s16x8 af = *(const s16x8*)&fb[(m0 + lr) * FBS + k0 + lg * 8];
                s16x8 bf = *(const s16x8*)&w2T[(n0 + lr) * 256 + k0 + lg * 8];
                fa0 = __builtin_amdgcn_mfma_f32_16x16x32_bf16(af, bf, fa0, 0, 0, 0);
            }
        }
        {
            const int m0 = (i1 % 3) << 4, n0 = (i1 / 3) << 4;
            #pragma unroll 4
            for (int k0 = 0; k0 < FF_; k0 += 32) {
                s16x8 af = *(const s16x8*)&fb[(m0 + lr) * FBS + k0 + lg * 8];
                s16x8 bf = *(const s16x8*)&w2T[(n0 + lr) * 256 + k0 + lg * 8];
                fa1 = __builtin_amdgcn_mfma_f32_16x16x32_bf16(af, bf, fa1, 0, 0, 0);
            }
        }
        {
            const int m0 = (i2 % 3) << 4, n0 = (i2 / 3) << 4;
            #pragma unroll 4
            for (int k0 = 0; k0 < FF_; k0 += 32) {
                s16x8 af = *(const s16x8*)&fb[(m0 + lr) * FBS + k0 + lg * 8];
                s16x8 bf = *(const s16x8*)&w2T[(n0 + lr) * 256 + k0 + lg * 8];
                fa2 = __builtin_amdgcn_mfma_f32_16x16x32_bf16(af, bf, fa2, 0, 0, 0);
            }
        }
    }
    __syncthreads();                                     // B7 (fb dead)
    {
        auto t2_tile = [&](int id, const f32x4& fa) {
            const int m0 = (id % 3) << 4, n0 = (id / 3) << 4;
            const int col = n0 + lr;
            const float bias = b2[col];
            #pragma unroll
            for (int r = 0; r < 4; ++r) {
                int row = m0 + lg * 4 + r;
                if (row < S_)
                    t2[row * LDH + col] = fa[r] + bias + bf2f(hb[row * HBS + col]);
            }
        };
        t2_tile(we, fa0);
        t2_tile(we + 4, fa1);
        t2_tile(we + 8, fa2);
    }
    __syncthreads();                                     // B8

    // ---- 8. LN2 (8 lanes/row): 360 slots over 256 threads -> out -------
    {
        for (int slot = te; slot < S_ * 8; slot += 256) {
            const int row = slot >> 3, d0 = (slot & 7) << 3;
            float4 v1 = *(const float4*)&t2[row * LDH + d0];
            float4 v2 = *(const float4*)&t2[row * LDH + d0 + 4];
            float s  = v1.x + v1.y + v1.z + v1.w + v2.x + v2.y + v2.z + v2.w;
            float s2 = v1.x*v1.x + v1.y*v1.y + v1.z*v1.z + v1.w*v1.w +
                       v2.x*v2.x + v2.y*v2.y + v2.z*v2.z + v2.w*v2.w;
            s  += __shfl_xor(s, 1);  s  += __shfl_xor(s, 2);  s  += __shfl_xor(s, 4);
            s2 += __shfl_xor(s2, 1); s2 += __shfl_xor(s2, 2); s2 += __shfl_xor(s2, 4);
            float mean = s * (1.0f / 64.0f);
            float var  = s2 * (1.0f / 64.0f) - mean * mean;
            float rstd = rsqrtf(var + 1e-5f);
            float4 g1 = *(const float4*)&ln2g[d0], g2 = *(const float4*)&ln2g[d0 + 4];
            float4 b1v = *(const float4*)&ln2b[d0], b2v = *(const float4*)&ln2b[d0 + 4];
            float4 o1, o2;
            o1.x = (v1.x - mean) * rstd * g1.x + b1v.x;
            o1.y = (v1.y - mean) * rstd * g1.y + b1v.y;
            o1.z = (v1.z - mean) * rstd * g1.z + b1v.z;
            o1.w = (v1.w - mean) * rstd * g1.w + b1v.w;
            o2.x = (v2.x - mean) * rstd * g2.x + b2v.x;
            o2.y = (v2.y - mean) * rstd * g2.y + b2v.y;
            o2.z = (v2.z - mean) * rstd * g2.z + b2v.z;
            o2.w = (v2.w - mean) * rstd * g2.w + b2v.w;
            float* op = out + e * (S_ * D_) + row * 64 + d0;
            *(float4*)op = o1;
            *(float4*)(op + 4) = o2;
        }
    }
}

extern "C" void kernel_launch(void* const* d_in, const int* in_sizes, int n_in,
                              void* d_out, int out_size, void* d_ws, size_t ws_size,
                              hipStream_t stream) {
    const float* x    = (const float*)d_in[0];
    const float* Wq   = (const float*)d_in[1];
    const float* bq   = (const float*)d_in[2];
    const float* Wk   = (const float*)d_in[3];
    const float* bk   = (const float*)d_in[4];
    const float* Wv   = (const float*)d_in[5];
    const float* bv   = (const float*)d_in[6];
    const float* Wo   = (const float*)d_in[7];
    const float* bo   = (const float*)d_in[8];
    const float* ln1g = (const float*)d_in[9];
    const float* ln1b = (const float*)d_in[10];
    const float* W1   = (const float*)d_in[11];
    const float* b1   = (const float*)d_in[12];
    const float* W2   = (const float*)d_in[13];
    const float* b2   = (const float*)d_in[14];
    const float* ln2g = (const float*)d_in[15];
    const float* ln2b = (const float*)d_in[16];
    float* out = (float*)d_out;

    hipLaunchKernelGGL(prep_kernel, dim3(64), dim3(256), 0, stream,
                       Wq, Wk, Wv, Wo, W1, W2, d_ws);
    hipLaunchKernelGGL(encoder_kernel, dim3(NB / 2), dim3(512), 0, stream,
                       x, bq, bk, bv, bo, ln1g, ln1b, b1, b2, ln2g, ln2b,
                       d_ws, out);
}

// Round 22
// 299.058 us; speedup vs baseline: 1.0591x; 1.0591x over previous
//
#include <hip/hip_runtime.h>
#include <hip/hip_bf16.h>
#include <math.h>

#define NB 8192
#define S_ 45
#define D_ 64
#define FF_ 256
#define LDH 68     // f32 row stride t1/t2
#define HBS 72     // bf16 row stride hb/qb/kb/ob (144 B)
#define VTS 72     // bf16 row stride vT [72][72]
#define FBS 280    // bf16 row stride fb full tile [48][280]

typedef __attribute__((ext_vector_type(4))) float f32x4;
typedef __attribute__((ext_vector_type(8))) short s16x8;
typedef __attribute__((ext_vector_type(4))) short s16x4;

// ws layout (bytes): pe f32 [45*64] @0 ; WqkvT bf16 [192][64] @11520 ;
// WoT bf16 [64][64] @36096 ; W1T bf16 [256][64] @44288 ; W2T bf16 [64][256] @77056
#define WS_QKV 11520
#define WS_WO  36096
#define WS_W1  44288
#define WS_W2  77056

__device__ inline short f2bf(float f) {   // HW RNE f32->bf16
    __hip_bfloat16 h = __float2bfloat16(f);
    return *reinterpret_cast<short*>(&h);
}
__device__ inline float bf2f(short s) {
    union { unsigned u; float f; } c;
    c.u = ((unsigned)(unsigned short)s) << 16;
    return c.f;
}

__global__ void prep_kernel(const float* __restrict__ Wq, const float* __restrict__ Wk,
                            const float* __restrict__ Wv, const float* __restrict__ Wo,
                            const float* __restrict__ W1, const float* __restrict__ W2,
                            void* __restrict__ ws) {
    float* pe   = (float*)ws;
    short* wqkv = (short*)((char*)ws + WS_QKV);
    short* wo   = (short*)((char*)ws + WS_WO);
    short* w1   = (short*)((char*)ws + WS_W1);
    short* w2   = (short*)((char*)ws + WS_W2);
    int i = blockIdx.x * 256 + threadIdx.x;
    if (i < S_ * D_) {                       // positional encoding (f32)
        int s = i / D_, d = i % D_;
        float div = expf(-logf(10000.0f) * (float)(d & ~1) / (float)D_);
        float ang = (float)s * div;
        pe[i] = (d & 1) ? cosf(ang) : sinf(ang);
    }
    if (i < 12288) {                         // WqkvT[n][k] = W{q,k,v}[k][n&63]
        int n = i >> 6, k = i & 63;
        const float* W = (n < 64) ? Wq : (n < 128 ? Wk : Wv);
        wqkv[i] = f2bf(W[k * 64 + (n & 63)]);
    }
    if (i < 4096) {                          // WoT[n][k] = Wo[k][n]
        int n = i >> 6, k = i & 63;
        wo[i] = f2bf(Wo[k * 64 + n]);
    }
    if (i < 16384) {
        int n = i >> 6, k = i & 63;          // W1T[n][k] = W1[k][n]
        w1[i] = f2bf(W1[k * FF_ + n]);
        int n2 = i >> 8, k2 = i & 255;       // W2T[n][k] = W2[k][n]
        w2[i] = f2bf(W2[k2 * 64 + n2]);
    }
}

__launch_bounds__(512, 1)
__global__ void encoder_kernel(
    const float* __restrict__ x,
    const float* __restrict__ bq, const float* __restrict__ bk,
    const float* __restrict__ bv, const float* __restrict__ bo,
    const float* __restrict__ ln1g, const float* __restrict__ ln1b,
    const float* __restrict__ b1, const float* __restrict__ b2,
    const float* __restrict__ ln2g, const float* __restrict__ ln2b,
    const void* __restrict__ ws,
    float* __restrict__ out)
{
    const float* pe    = (const float*)ws;
    const short* wqkvT = (const short*)((const char*)ws + WS_QKV);
    const short* woT   = (const short*)((const char*)ws + WS_WO);
    const short* w1T   = (const short*)((const char*)ws + WS_W1);
    const short* w2T   = (const short*)((const char*)ws + WS_W2);

    // LDS pool 38016 B -> 4 blocks/CU (R16/R19 verified structure):
    //  @0     hb bf16 [48][72] ; @6912 qb | t1/t2 f32 | fb ; @13824 kb ;
    //  @20736 vT bf16 [72][72] ; @31104 ob bf16 [48][72]
    __shared__ __align__(16) char pool[38016];
    short* hb = (short*)pool;
    short* qb = (short*)(pool + 6912);
    short* kb = (short*)(pool + 13824);
    short* vT = (short*)(pool + 20736);
    short* ob = (short*)(pool + 31104);
    float* t1 = (float*)(pool + 6912);
    short* fb = (short*)(pool + 6912);
    float* t2 = (float*)(pool + 6912);

    const int t = threadIdx.x;
    const int b = blockIdx.x;
    const int w = t >> 6, l = t & 63;
    const int lr = l & 15, lg = l >> 4;   // MFMA frag coords
    const s16x8 zero8 = {0, 0, 0, 0, 0, 0, 0, 0};

    // ---- 1. h = x + pe -> hb (bf16); zero pad rows ---------------------
    {
        const float4* x4 = (const float4*)(x + (size_t)b * (S_ * D_));
        const float4* p4 = (const float4*)pe;
        for (int i = t; i < S_ * D_ / 4; i += 512) {
            int r = i >> 4, c4 = (i & 15) << 2;
            float4 a = x4[i], p = p4[i];
            s16x4 hv16 = { f2bf(a.x + p.x), f2bf(a.y + p.y),
                           f2bf(a.z + p.z), f2bf(a.w + p.w) };
            *(s16x4*)&hb[r * HBS + c4] = hv16;
        }
        for (int i = t; i < 3 * HBS; i += 512) hb[45 * HBS + i] = 0;
    }
    __syncthreads();                                     // B1

    // ---- 2. fused QKV via MFMA -> qb (bf16 scaled), kb (bf16), vT ------
    {
        const float SC2 = 0.35355339059327373f * 1.44269504088896340f; // 1/sqrt(8)*log2e
        for (int id = w; id < 36; id += 8) {
            const int m0 = (id % 3) << 4, n0 = (id / 3) << 4;
            f32x4 acc = {0.f, 0.f, 0.f, 0.f};
            #pragma unroll
            for (int k0 = 0; k0 < 64; k0 += 32) {
                s16x8 af = *(const s16x8*)&hb[(m0 + lr) * HBS + k0 + lg * 8];
                s16x8 bf = *(const s16x8*)&wqkvT[(n0 + lr) * 64 + k0 + lg * 8];
                acc = __builtin_amdgcn_mfma_f32_16x16x32_bf16(af, bf, acc, 0, 0, 0);
            }
            if (n0 < 64) {                       // q' = (q+bq)*SC2
                const float bias = bq[n0 + lr];
                #pragma unroll
                for (int r = 0; r < 4; ++r)
                    qb[(m0 + lg * 4 + r) * HBS + n0 + lr] = f2bf((acc[r] + bias) * SC2);
            } else if (n0 < 128) {               // k
                const int cc = n0 - 64 + lr;
                const float bias = bk[cc];
                #pragma unroll
                for (int r = 0; r < 4; ++r)
                    kb[(m0 + lg * 4 + r) * HBS + cc] = f2bf(acc[r] + bias);
            } else {                             // v -> vT[d][kr] (K-axis pads
                const int cc = n0 - 128 + lr;    //  finite; P masks kr>=45)
                const float bias = bv[cc];
                s16x4 vv = { f2bf(acc[0] + bias), f2bf(acc[1] + bias),
                             f2bf(acc[2] + bias), f2bf(acc[3] + bias) };
                *(s16x4*)&vT[cc * VTS + m0 + lg * 4] = vv;
            }
        }
    }
    __syncthreads();                                     // B2

    // ---- 3. attention: swapped QK^T + in-register softmax (R16-exact) --
    {
        const int hd = w << 3;
        s16x8 pv_b0 = *(const s16x8*)&vT[(hd + lr) * VTS + lg * 8];          // kr 0-31
        s16x8 pv_b1 = (lg < 2) ? *(const s16x8*)&vT[(hd + lr) * VTS + 32 + lg * 8]
                               : zero8;                                      // kr 32-47
        s16x8 kaf[3];
        #pragma unroll
        for (int tm = 0; tm < 3; ++tm)
            kaf[tm] = (lg == 0) ? *(const s16x8*)&kb[(tm * 16 + lr) * HBS + hd] : zero8;
        #pragma unroll
        for (int tn = 0; tn < 3; ++tn) {
            s16x8 qbf = (lg == 0) ? *(const s16x8*)&qb[(tn * 16 + lr) * HBS + hd] : zero8;
            f32x4 S[3];
            #pragma unroll
            for (int tm = 0; tm < 3; ++tm) {
                f32x4 z = {0.f, 0.f, 0.f, 0.f};
                S[tm] = __builtin_amdgcn_mfma_f32_16x16x32_bf16(kaf[tm], qbf, z, 0, 0, 0);
            }
            float psum = 0.f;
            #pragma unroll
            for (int tm = 0; tm < 3; ++tm) {
                #pragma unroll
                for (int r = 0; r < 4; ++r) {
                    float e = __builtin_amdgcn_exp2f(S[tm][r]);
                    if (tm == 2) e = (lg * 4 + r >= 13) ? 0.f : e;  // kr>=45 mask
                    S[tm][r] = e;
                    psum += e;
                }
            }
            float s = psum;
            s += __shfl_xor(s, 16);
            s += __shfl_xor(s, 32);
            float inv = 1.0f / s;
            unsigned pk0[3], pk1[3];   // bf16x2 packed P (truncation), per tm
            #pragma unroll
            for (int tm = 0; tm < 3; ++tm) {
                float a0 = S[tm][0] * inv, a1 = S[tm][1] * inv;
                float a2 = S[tm][2] * inv, a3 = S[tm][3] * inv;
                pk0[tm] = (__float_as_uint(a0) >> 16) | (__float_as_uint(a1) & 0xFFFF0000u);
                pk1[tm] = (__float_as_uint(a2) >> 16) | (__float_as_uint(a3) & 0xFFFF0000u);
            }
            const int srcA = lr + ((lg & 1) << 5);
            const int srcB = srcA + 16;
            unsigned gA0[3], gA1[3], gB0[3], gB1[3];
            #pragma unroll
            for (int tm = 0; tm < 3; ++tm) {
                gA0[tm] = (unsigned)__shfl((int)pk0[tm], srcA);
                gA1[tm] = (unsigned)__shfl((int)pk1[tm], srcA);
                gB0[tm] = (unsigned)__shfl((int)pk0[tm], srcB);
                gB1[tm] = (unsigned)__shfl((int)pk1[tm], srcB);
            }
            const bool tm1 = (lg >> 1) != 0;
            union { unsigned u[4]; s16x8 v; } a1c, a2c;
            a1c.u[0] = tm1 ? gA0[1] : gA0[0];
            a1c.u[1] = tm1 ? gA1[1] : gA1[0];
            a1c.u[2] = tm1 ? gB0[1] : gB0[0];
            a1c.u[3] = tm1 ? gB1[1] : gB1[0];
            const bool lo = (lg < 2);
            a2c.u[0] = lo ? gA0[2] : 0u;
            a2c.u[1] = lo ? gA1[2] : 0u;
            a2c.u[2] = lo ? gB0[2] : 0u;
            a2c.u[3] = lo ? gB1[2] : 0u;
            f32x4 z = {0.f, 0.f, 0.f, 0.f};
            f32x4 O = __builtin_amdgcn_mfma_f32_16x16x32_bf16(a1c.v, pv_b0, z, 0, 0, 0);
            O = __builtin_amdgcn_mfma_f32_16x16x32_bf16(a2c.v, pv_b1, O, 0, 0, 0);
            if (lr < 8) {
                #pragma unroll
                for (int r = 0; r < 4; ++r) {
                    int row = tn * 16 + lg * 4 + r;
                    if (row < S_) ob[row * HBS + hd + lr] = f2bf(O[r]);
                }
            }
        }
    }
    __syncthreads();                                     // B3

    // ---- 4. t1 = o @ Wo + bo + h (residual from hb), MFMA -> t1 (f32) --
    {
        for (int id = w; id < 12; id += 8) {
            const int m0 = (id % 3) << 4, n0 = (id / 3) << 4;
            f32x4 acc = {0.f, 0.f, 0.f, 0.f};
            #pragma unroll
            for (int k0 = 0; k0 < 64; k0 += 32) {
                s16x8 af = *(const s16x8*)&ob[(m0 + lr) * HBS + k0 + lg * 8];
                s16x8 bf = *(const s16x8*)&woT[(n0 + lr) * 64 + k0 + lg * 8];
                acc = __builtin_amdgcn_mfma_f32_16x16x32_bf16(af, bf, acc, 0, 0, 0);
            }
            const int col = n0 + lr;
            const float bias = bo[col];
            #pragma unroll
            for (int r = 0; r < 4; ++r) {
                int row = m0 + lg * 4 + r;
                if (row < S_)
                    t1[row * LDH + col] = acc[r] + bias + bf2f(hb[row * HBS + col]);
            }
        }
    }
    __syncthreads();                                     // B4

    // ---- 5. LN1 (8 lanes/row, 3-stage shfl): t1 -> h2 (hb bf16) --------
    {
        if (t < S_ * 8) {
            const int row = t >> 3, d0 = (t & 7) << 3;
            float4 v1 = *(const float4*)&t1[row * LDH + d0];
            float4 v2 = *(const float4*)&t1[row * LDH + d0 + 4];
            float s  = v1.x + v1.y + v1.z + v1.w + v2.x + v2.y + v2.z + v2.w;
            float s2 = v1.x*v1.x + v1.y*v1.y + v1.z*v1.z + v1.w*v1.w +
                       v2.x*v2.x + v2.y*v2.y + v2.z*v2.z + v2.w*v2.w;
            s  += __shfl_xor(s, 1);  s  += __shfl_xor(s, 2);  s  += __shfl_xor(s, 4);
            s2 += __shfl_xor(s2, 1); s2 += __shfl_xor(s2, 2); s2 += __shfl_xor(s2, 4);
            float mean = s * (1.0f / 64.0f);
            float var  = s2 * (1.0f / 64.0f) - mean * mean;
            float rstd = rsqrtf(var + 1e-5f);
            float4 g1 = *(const float4*)&ln1g[d0], g2 = *(const float4*)&ln1g[d0 + 4];
            float4 b1v = *(const float4*)&ln1b[d0], b2v = *(const float4*)&ln1b[d0 + 4];
            s16x8 o16;
            o16[0] = f2bf((v1.x - mean) * rstd * g1.x + b1v.x);
            o16[1] = f2bf((v1.y - mean) * rstd * g1.y + b1v.y);
            o16[2] = f2bf((v1.z - mean) * rstd * g1.z + b1v.z);
            o16[3] = f2bf((v1.w - mean) * rstd * g1.w + b1v.w);
            o16[4] = f2bf((v2.x - mean) * rstd * g2.x + b2v.x);
            o16[5] = f2bf((v2.y - mean) * rstd * g2.y + b2v.y);
            o16[6] = f2bf((v2.z - mean) * rstd * g2.z + b2v.z);
            o16[7] = f2bf((v2.w - mean) * rstd * g2.w + b2v.w);
            *(s16x8*)&hb[row * HBS + d0] = o16;
        }
    }
    __syncthreads();                                     // B5

    // ---- 6. FFN1 full-width: f = relu(h2 @ W1 + b1) -> fb [48][280] ----
    {
        for (int id = w; id < 48; id += 8) {
            const int m0 = (id % 3) << 4, nl = (id / 3) << 4;
            f32x4 acc = {0.f, 0.f, 0.f, 0.f};
            #pragma unroll
            for (int k0 = 0; k0 < 64; k0 += 32) {
                s16x8 af = *(const s16x8*)&hb[(m0 + lr) * HBS + k0 + lg * 8];
                s16x8 bf = *(const s16x8*)&w1T[(nl + lr) * 64 + k0 + lg * 8];
                acc = __builtin_amdgcn_mfma_f32_16x16x32_bf16(af, bf, acc, 0, 0, 0);
            }
            const float bias = b1[nl + lr];
            #pragma unroll
            for (int r = 0; r < 4; ++r) {
                int row = m0 + lg * 4 + r;
                if (row < S_)
                    fb[row * FBS + nl + lr] = f2bf(fmaxf(acc[r] + bias, 0.f));
            }
        }
    }
    __syncthreads();                                     // B6

    // ---- 7. FFN2 full-K (single-acc chains): ---------------------------
    f32x4 facc0 = {0.f, 0.f, 0.f, 0.f};
    f32x4 facc1 = {0.f, 0.f, 0.f, 0.f};
    {
        const int m0 = (w % 3) << 4, n0 = (w / 3) << 4;
        #pragma unroll 4
        for (int k0 = 0; k0 < FF_; k0 += 32) {
            s16x8 af = *(const s16x8*)&fb[(m0 + lr) * FBS + k0 + lg * 8];
            s16x8 bf = *(const s16x8*)&w2T[(n0 + lr) * 256 + k0 + lg * 8];
            facc0 = __builtin_amdgcn_mfma_f32_16x16x32_bf16(af, bf, facc0, 0, 0, 0);
        }
        if (w < 4) {
            const int id = w + 8;
            const int m1 = (id % 3) << 4, n1 = (id / 3) << 4;
            #pragma unroll 4
            for (int k0 = 0; k0 < FF_; k0 += 32) {
                s16x8 af = *(const s16x8*)&fb[(m1 + lr) * FBS + k0 + lg * 8];
                s16x8 bf = *(const s16x8*)&w2T[(n1 + lr) * 256 + k0 + lg * 8];
                facc1 = __builtin_amdgcn_mfma_f32_16x16x32_bf16(af, bf, facc1, 0, 0, 0);
            }
        }
    }
    __syncthreads();                                     // B7 (fb dead)
    {
        const int m0 = (w % 3) << 4, n0 = (w / 3) << 4;
        const int col = n0 + lr;
        const float bias = b2[col];
        #pragma unroll
        for (int r = 0; r < 4; ++r) {
            int row = m0 + lg * 4 + r;
            if (row < S_)
                t2[row * LDH + col] = facc0[r] + bias + bf2f(hb[row * HBS + col]);
        }
        if (w < 4) {
            const int id = w + 8;
            const int m1 = (id % 3) << 4, n1 = (id / 3) << 4;
            const int col1 = n1 + lr;
            const float bias1 = b2[col1];
            #pragma unroll
            for (int r = 0; r < 4; ++r) {
                int row = m1 + lg * 4 + r;
                if (row < S_)
                    t2[row * LDH + col1] = facc1[r] + bias1 + bf2f(hb[row * HBS + col1]);
            }
        }
    }
    __syncthreads();                                     // B8

    // ---- 8. LN2 (8 lanes/row, 3-stage shfl): t2 -> out -----------------
    {
        if (t < S_ * 8) {
            const int row = t >> 3, d0 = (t & 7) << 3;
            float4 v1 = *(const float4*)&t2[row * LDH + d0];
            float4 v2 = *(const float4*)&t2[row * LDH + d0 + 4];
            float s  = v1.x + v1.y + v1.z + v1.w + v2.x + v2.y + v2.z + v2.w;
            float s2 = v1.x*v1.x + v1.y*v1.y + v1.z*v1.z + v1.w*v1.w +
                       v2.x*v2.x + v2.y*v2.y + v2.z*v2.z + v2.w*v2.w;
            s  += __shfl_xor(s, 1);  s  += __shfl_xor(s, 2);  s  += __shfl_xor(s, 4);
            s2 += __shfl_xor(s2, 1); s2 += __shfl_xor(s2, 2); s2 += __shfl_xor(s2, 4);
            float mean = s * (1.0f / 64.0f);
            float var  = s2 * (1.0f / 64.0f) - mean * mean;
            float rstd = rsqrtf(var + 1e-5f);
            float4 g1 = *(const float4*)&ln2g[d0], g2 = *(const float4*)&ln2g[d0 + 4];
            float4 b1v = *(const float4*)&ln2b[d0], b2v = *(const float4*)&ln2b[d0 + 4];
            float4 o1, o2;
            o1.x = (v1.x - mean) * rstd * g1.x + b1v.x;
            o1.y = (v1.y - mean) * rstd * g1.y + b1v.y;
            o1.z = (v1.z - mean) * rstd * g1.z + b1v.z;
            o1.w = (v1.w - mean) * rstd * g1.w + b1v.w;
            o2.x = (v2.x - mean) * rstd * g2.x + b2v.x;
            o2.y = (v2.y - mean) * rstd * g2.y + b2v.y;
            o2.z = (v2.z - mean) * rstd * g2.z + b2v.z;
            o2.w = (v2.w - mean) * rstd * g2.w + b2v.w;
            float* op = out + (size_t)b * (S_ * D_) + row * 64 + d0;
            *(float4*)op = o1;
            *(float4*)(op + 4) = o2;
        }
    }
}

extern "C" void kernel_launch(void* const* d_in, const int* in_sizes, int n_in,
                              void* d_out, int out_size, void* d_ws, size_t ws_size,
                              hipStream_t stream) {
    const float* x    = (const float*)d_in[0];
    const float* Wq   = (const float*)d_in[1];
    const float* bq   = (const float*)d_in[2];
    const float* Wk   = (const float*)d_in[3];
    const float* bk   = (const float*)d_in[4];
    const float* Wv   = (const float*)d_in[5];
    const float* bv   = (const float*)d_in[6];
    const float* Wo   = (const float*)d_in[7];
    const float* bo   = (const float*)d_in[8];
    const float* ln1g = (const float*)d_in[9];
    const float* ln1b = (const float*)d_in[10];
    const float* W1   = (const float*)d_in[11];
    const float* b1   = (const float*)d_in[12];
    const float* W2   = (const float*)d_in[13];
    const float* b2   = (const float*)d_in[14];
    const float* ln2g = (const float*)d_in[15];
    const float* ln2b = (const float*)d_in[16];
    float* out = (float*)d_out;

    hipLaunchKernelGGL(prep_kernel, dim3(64), dim3(256), 0, stream,
                       Wq, Wk, Wv, Wo, W1, W2, d_ws);
    hipLaunchKernelGGL(encoder_kernel, dim3(NB), dim3(512), 0, stream,
                       x, bq, bk, bv, bo, ln1g, ln1b, b1, b2, ln2g, ln2b,
                       d_ws, out);
}